// Round 1
// baseline (221.110 us; speedup 1.0000x reference)
//
#include <hip/hip_runtime.h>

// One WAVE (64 lanes) per ray; 256-thread block = 4 fully-independent rays
// (no __syncthreads — s_zedge is per-wave, ordered by wave-local lgkmcnt).
// T0=64 coarse intervals, TF=128 fine samples; 2 fine samples per lane.
// Output row per ray: [image.rgb (3), depth (1), contracted xyz (3*TF)] = 388 f32.
//
// R4 was latency-bound: every __shfl lowered to ds_bpermute (~35cy LDS-pipe
// latency), and the two 6-step scans + 7-step x4 reduction put ~23 of them on
// the per-ray serial critical path. R5 replaces ALL cross-lane ops with DPP
// (v_add/mul_f32 dpp row_shr / row_bcast15 / row_bcast31, wf_sr1 for the
// exclusive shift, v_readlane for the wave total) — pure-VALU ~4cy/step, no
// lgkmcnt, bitwise-exact neighbor handoff so the 129-edge interval partition
// stays an exact partition. Remaining LDS traffic: only the z-edge scatter.

constexpr int kT0 = 64;
constexpr int kTF = 128;
constexpr int kRaysPerBlock = 4;   // 4 waves/block

// ---- DPP primitives (gfx9/CDNA encodings) -------------------------------
// ROW_SHR|n = 0x110|n, WF_SR1 = 0x138, ROW_BCAST15 = 0x142, ROW_BCAST31 = 0x143
template <int Ctrl, int RowMask>
__device__ __forceinline__ float dpp_mov(float x, float oldv) {
    // row_mask-disabled rows and invalid source lanes keep `oldv`
    // (bound_ctrl=false), which we set to the op identity.
    return __int_as_float(__builtin_amdgcn_update_dpp(
        __float_as_int(oldv), __float_as_int(x), Ctrl, RowMask, 0xf, false));
}

// wave64 inclusive sum scan: 6 VALU ops, lane63 ends with the total.
__device__ __forceinline__ float wave_iscan_add(float x) {
    x += dpp_mov<0x111, 0xf>(x, 0.0f);   // row_shr:1
    x += dpp_mov<0x112, 0xf>(x, 0.0f);   // row_shr:2
    x += dpp_mov<0x114, 0xf>(x, 0.0f);   // row_shr:4
    x += dpp_mov<0x118, 0xf>(x, 0.0f);   // row_shr:8
    x += dpp_mov<0x142, 0xa>(x, 0.0f);   // row_bcast15 -> rows 1,3
    x += dpp_mov<0x143, 0xc>(x, 0.0f);   // row_bcast31 -> rows 2,3
    return x;
}

// wave64 inclusive product scan (identity 1.0)
__device__ __forceinline__ float wave_iscan_mul(float x) {
    x *= dpp_mov<0x111, 0xf>(x, 1.0f);
    x *= dpp_mov<0x112, 0xf>(x, 1.0f);
    x *= dpp_mov<0x114, 0xf>(x, 1.0f);
    x *= dpp_mov<0x118, 0xf>(x, 1.0f);
    x *= dpp_mov<0x142, 0xa>(x, 1.0f);
    x *= dpp_mov<0x143, 0xc>(x, 1.0f);
    return x;
}

// whole-wave shift right by 1 (lane k gets lane k-1's value, lane0 gets oldv)
template <int Dummy = 0>
__device__ __forceinline__ float wave_shr1(float x, float oldv) {
    return dpp_mov<0x138, 0xf>(x, oldv);  // wf_sr1
}

__global__ __launch_bounds__(256)
void nerf_render_kernel(const float* __restrict__ rays_o,
                        const float* __restrict__ rays_d,
                        const float* __restrict__ aabb,
                        const float* __restrict__ weights,   // [N, 64]
                        const float* __restrict__ sigmas,    // [N, 128]
                        const float* __restrict__ rgbs,      // [N, 128, 3]
                        float* __restrict__ out)             // [N, 388]
{
    const int lane = threadIdx.x & 63;
    const int wid  = threadIdx.x >> 6;
    const int ray  = blockIdx.x * kRaysPerBlock + wid;

    __shared__ float s_zedge[kRaysPerBlock][kTF + 2];   // rows padded to 130 -> 8B-aligned

    // ---- issue ALL global streams up front (consume order: weights, sigma, rgb) ----
    const float wraw = weights[(size_t)ray * kT0 + lane];
    const float2 sg  = *(const float2*)(sigmas + (size_t)ray * kTF + 2 * lane);
    const float* rgb_row = rgbs + (size_t)ray * (kTF * 3) + 6 * lane;  // 8B-aligned
    const float2 rgA = *(const float2*)(rgb_row + 0);   // r0 g0
    const float2 rgB = *(const float2*)(rgb_row + 2);   // b0 r1
    const float2 rgC = *(const float2*)(rgb_row + 4);   // g1 b1

    // ---- ray-AABB near/far (wave-uniform; overlaps weights load) ----
    const float ox = rays_o[ray * 3 + 0], oy = rays_o[ray * 3 + 1], ozr = rays_o[ray * 3 + 2];
    const float dx = rays_d[ray * 3 + 0], dy = rays_d[ray * 3 + 1], dzr = rays_d[ray * 3 + 2];
    float near, far;
    {
        const float rx = __builtin_amdgcn_rcpf(dx + 1e-15f);
        const float ry = __builtin_amdgcn_rcpf(dy + 1e-15f);
        const float rz = __builtin_amdgcn_rcpf(dzr + 1e-15f);
        const float t0x = (aabb[0] - ox) * rx, t1x = (aabb[3] - ox) * rx;
        const float t0y = (aabb[1] - oy) * ry, t1y = (aabb[4] - oy) * ry;
        const float t0z = (aabb[2] - ozr) * rz, t1z = (aabb[5] - ozr) * rz;
        near = fmaxf(fmaxf(fminf(t0x, t1x), fminf(t0y, t1y)), fminf(t0z, t1z));
        far  = fminf(fminf(fmaxf(t0x, t1x), fmaxf(t0y, t1y)), fmaxf(t0z, t1z));
        if (far < near) { near = 1e9f; far = 1e9f; }
        near = fmaxf(near, 0.05f);
    }
    const float range = far - near;

    // ---- CDF inclusive scan over coarse weights (DPP, no LDS) ----
    const float scan  = wave_iscan_add(wraw + 0.01f);
    const float total = __int_as_float(__builtin_amdgcn_readlane(__float_as_int(scan), 63));
    const float c_hi  = fminf(scan * __builtin_amdgcn_rcpf(total), 1.0f); // cdf[lane+1]
    const float c_lo  = wave_shr1<>(c_hi, 0.0f);                          // cdf[lane], bitwise-exact neighbor

    // ---- interval-owner scatter of the 129 fine bin edges ----
    // lane k owns u in [cdf[k], cdf[k+1]); u_j = (j+0.5)/129.
    // Adjacent lanes compute ceil of the bitwise-identical cdf value
    // -> exact partition of j in [0,129).
    {
        const float b_lo = near + range * ((float)lane * (1.0f / kT0));
        const float bw = range * (1.0f / kT0);
        int j_start = (int)ceilf(fmaf(129.0f, c_lo, -0.5f));
        int j_end   = (int)ceilf(fmaf(129.0f, c_hi, -0.5f));
        j_start = j_start < 0 ? 0 : j_start;
        j_end   = j_end > (kTF + 1) ? (kTF + 1) : j_end;
        const float rdenom = __builtin_amdgcn_rcpf(c_hi - c_lo);
        float fj = (float)j_start + 0.5f;
        for (int j = j_start; j < j_end; ++j, fj += 1.0f) {
            const float u = fj * (1.0f / 129.0f);
            float t = (u - c_lo) * rdenom;
            t = fminf(fmaxf(t, 0.0f), 1.0f);
            s_zedge[wid][j] = fmaf(t, bw, b_lo);
        }
    }
    // wave-local LDS ordering: all of this wave's ds_writes drained before reads.
    // (s_zedge[wid] is touched by this wave only -> no block barrier needed.)
    __builtin_amdgcn_wave_barrier();
    __asm__ volatile("s_waitcnt lgkmcnt(0)" ::: "memory");
    __builtin_amdgcn_wave_barrier();

    // ---- per-lane: fine samples 2*lane and 2*lane+1 ----
    const float2 ze01 = *(const float2*)&s_zedge[wid][2 * lane];  // 8B-aligned (row=130)
    const float  ze2  = s_zedge[wid][2 * lane + 2];
    const float d0 = ze01.y - ze01.x, d1 = ze2 - ze01.y;
    const float z0 = 0.5f * (ze01.x + ze01.y), z1 = 0.5f * (ze01.y + ze2);

    const float e0 = __expf(-sg.x * d0);
    const float e1 = __expf(-sg.y * d1);
    const float a0 = 1.0f - e0, a1 = 1.0f - e1;
    const float f0 = e0 + 1e-10f;
    const float f1 = e1 + 1e-10f;

    // ---- transmittance: wave64 product scan (DPP) + exact exclusive shift ----
    const float ps   = wave_iscan_mul(f0 * f1);
    const float excl = wave_shr1<>(ps, 1.0f);
    const float w0 = a0 * excl;
    const float w1 = a1 * excl * f0;

    // ---- image/depth: 4 interleaved DPP scan-reductions; lane 63 holds totals ----
    float vr = wave_iscan_add(w0 * rgA.x + w1 * rgB.y);
    float vg = wave_iscan_add(w0 * rgA.y + w1 * rgC.x);
    float vb = wave_iscan_add(w0 * rgB.x + w1 * rgC.y);
    float vd = wave_iscan_add(w0 * z0 + w1 * z1);

    float* orow = out + (size_t)ray * (4 + kTF * 3);   // 16B-aligned (388*4=1552)
    if (lane == 63) {
        *(float4*)orow = make_float4(vr, vg, vb, vd);
    }

    // ---- contraction (branchless) + dwordx2 stores (6 consecutive floats/lane) ----
    float oxyz[6];
    #pragma unroll
    for (int s = 0; s < 2; ++s) {
        const float z = s ? z1 : z0;
        float px = ox  + dx  * z;
        float py = oy  + dy  * z;
        float pz = ozr + dzr * z;
        const float ax = fabsf(px), ay = fabsf(py), az = fabsf(pz);
        float mag; int idx;
        if (ax >= ay && ax >= az) { mag = ax; idx = 0; }
        else if (ay >= az)        { mag = ay; idx = 1; }
        else                      { mag = az; idx = 2; }
        const float inv    = __builtin_amdgcn_rcpf(mag);
        const bool  inside = mag < 1.0f;
        const float s_oth  = inside ? 1.0f : inv;
        const float s_max  = inside ? 1.0f : (2.0f - inv) * inv;
        oxyz[3 * s + 0] = px * ((idx == 0) ? s_max : s_oth);
        oxyz[3 * s + 1] = py * ((idx == 1) ? s_max : s_oth);
        oxyz[3 * s + 2] = pz * ((idx == 2) ? s_max : s_oth);
    }
    float* o = orow + 4 + 6 * lane;                    // 8B-aligned
    *(float2*)(o + 0) = make_float2(oxyz[0], oxyz[1]);
    *(float2*)(o + 2) = make_float2(oxyz[2], oxyz[3]);
    *(float2*)(o + 4) = make_float2(oxyz[4], oxyz[5]);
}

extern "C" void kernel_launch(void* const* d_in, const int* in_sizes, int n_in,
                              void* d_out, int out_size, void* d_ws, size_t ws_size,
                              hipStream_t stream) {
    const float* rays_o  = (const float*)d_in[0];
    const float* rays_d  = (const float*)d_in[1];
    const float* aabb    = (const float*)d_in[2];
    const float* weights = (const float*)d_in[3];
    const float* sigmas  = (const float*)d_in[4];
    const float* rgbs    = (const float*)d_in[5];
    float* out           = (float*)d_out;

    const int N = in_sizes[0] / 3;   // rays_o is [N,3]
    const int blocks = N / kRaysPerBlock;
    nerf_render_kernel<<<blocks, 256, 0, stream>>>(rays_o, rays_d, aabb, weights, sigmas, rgbs, out);
}